// Round 1
// baseline (144.255 us; speedup 1.0000x reference)
//
#include <hip/hip_runtime.h>
#include <hip/hip_bf16.h>

#define NN 646
#define FF 32768
#define HH 64
#define LL 128
#define TOT (NN*HH)          // 41344
#define OUTTOT (NN*LL)       // 82688
#define WT_STRIDE (FF + 32)  // padded bf16 row (break 64KB set aliasing)
#define KSPLIT 32
#define KSLICE (FF / KSPLIT) // 1024

typedef float f32x4 __attribute__((ext_vector_type(4)));
typedef short short8 __attribute__((ext_vector_type(8)));

__device__ __forceinline__ unsigned short f2bf(float f) {
  __hip_bfloat16 h = __float2bfloat16(f);
  return __builtin_bit_cast(unsigned short, h);
}

// ---- K0: transpose+convert [W1|LPw] (f32 [32768][64] each) -> wt bf16 [128][WT_STRIDE]
__global__ __launch_bounds__(256) void k_wt(const float* __restrict__ W1,
                                            const float* __restrict__ LPw,
                                            unsigned short* __restrict__ wt) {
  __shared__ float t[64][129];
  int k0 = blockIdx.x * 64;
  for (int idx = threadIdx.x; idx < 64 * 128; idx += 256) {
    int kk = idx >> 7, n = idx & 127;
    float v = (n < 64) ? W1[(size_t)(k0 + kk) * 64 + n]
                       : LPw[(size_t)(k0 + kk) * 64 + (n - 64)];
    t[kk][n] = v;
  }
  __syncthreads();
  for (int idx = threadIdx.x; idx < 64 * 128; idx += 256) {
    int kk = idx & 63, n = idx >> 6;
    wt[(size_t)n * WT_STRIDE + k0 + kk] = f2bf(t[kk][n]);
  }
}

// ---- K1: degrees -> dinv; also detect edge dtype (int64 vs int32)
__global__ __launch_bounds__(1024) void k_deg(const int* __restrict__ e32, int E,
                                              float* __restrict__ dinv,
                                              int* __restrict__ flag) {
  __shared__ int cnt[NN];
  __shared__ int orred;
  int tid = threadIdx.x;
  if (tid == 0) orred = 0;
  for (int i = tid; i < NN; i += 1024) cnt[i] = 0;
  __syncthreads();
  // int64 data: odd int32 words are hi-words == 0 (all values in [0,646))
  if (tid < E && e32[2 * tid + 1] != 0) atomicOr(&orred, 1);
  __syncthreads();
  bool i64 = (orred == 0);
  for (int e = tid; e < E; e += 1024) {
    int c = i64 ? e32[2 * E + 2 * e] : e32[E + e];
    atomicAdd(&cnt[c], 1);
  }
  __syncthreads();
  for (int i = tid; i < NN; i += 1024) dinv[i] = rsqrtf((float)(cnt[i] + 1));
  if (tid == 0) *flag = i64 ? 1 : 0;
}

// ---- K2: partial[ks][m][n] = x[m, ks*1024:(ks+1)*1024] @ wt^T slice  (bf16 MFMA)
__global__ __launch_bounds__(256) void k_gemm(const float* __restrict__ x,
                                              const unsigned short* __restrict__ wt,
                                              float* __restrict__ partial) {
  int mt = blockIdx.x;   // 0..20, 32 rows each
  int ks = blockIdx.y;   // 0..31
  int tid = threadIdx.x;
  int w = tid >> 6, l = tid & 63;
  int mh = w & 1, nh = w >> 1;
  int lr = l & 15, g = l >> 4;
  int row = mt * 32 + mh * 16 + lr;
  int rc = row < NN ? row : NN - 1;
  int kbase = ks * KSLICE + g * 8;
  const float* xp = x + (size_t)rc * FF + kbase;
  const unsigned short* wp0 = wt + (size_t)(nh * 64 + lr) * WT_STRIDE + kbase;
  const unsigned short* wp1 = wp0 + (size_t)16 * WT_STRIDE;
  const unsigned short* wp2 = wp0 + (size_t)32 * WT_STRIDE;
  const unsigned short* wp3 = wp0 + (size_t)48 * WT_STRIDE;
  f32x4 ac0 = {0.f, 0.f, 0.f, 0.f}, ac1 = ac0, ac2 = ac0, ac3 = ac0;
#pragma unroll 2
  for (int kk = 0; kk < KSLICE; kk += 32) {
    const float4* pa = reinterpret_cast<const float4*>(xp + kk);
    float4 a0 = pa[0], a1 = pa[1];
    short8 a;
    a[0] = (short)f2bf(a0.x); a[1] = (short)f2bf(a0.y);
    a[2] = (short)f2bf(a0.z); a[3] = (short)f2bf(a0.w);
    a[4] = (short)f2bf(a1.x); a[5] = (short)f2bf(a1.y);
    a[6] = (short)f2bf(a1.z); a[7] = (short)f2bf(a1.w);
    short8 b0 = *reinterpret_cast<const short8*>(wp0 + kk);
    short8 b1 = *reinterpret_cast<const short8*>(wp1 + kk);
    short8 b2 = *reinterpret_cast<const short8*>(wp2 + kk);
    short8 b3 = *reinterpret_cast<const short8*>(wp3 + kk);
    ac0 = __builtin_amdgcn_mfma_f32_16x16x32_bf16(a, b0, ac0, 0, 0, 0);
    ac1 = __builtin_amdgcn_mfma_f32_16x16x32_bf16(a, b1, ac1, 0, 0, 0);
    ac2 = __builtin_amdgcn_mfma_f32_16x16x32_bf16(a, b2, ac2, 0, 0, 0);
    ac3 = __builtin_amdgcn_mfma_f32_16x16x32_bf16(a, b3, ac3, 0, 0, 0);
  }
  int mbase = mt * 32 + mh * 16 + g * 4;
  int nb = nh * 64 + lr;
  float* pp = partial + (size_t)ks * OUTTOT;
#pragma unroll
  for (int j = 0; j < 4; ++j) {
    int m = mbase + j;
    if (m < NN) {
      pp[m * LL + nb +  0] = ac0[j];
      pp[m * LL + nb + 16] = ac1[j];
      pp[m * LL + nb + 32] = ac2[j];
      pp[m * LL + nb + 48] = ac3[j];
    }
  }
}

// ---- K3: reduce partials; cols 0..63 = x@W1 (no bias), 64..127 = x@LPw + LPb
__global__ __launch_bounds__(256) void k_red(const float* __restrict__ partial,
                                             const float* __restrict__ LPb,
                                             float* __restrict__ hcat) {
  int idx = blockIdx.x * 256 + threadIdx.x;
  float s = 0.f;
#pragma unroll
  for (int ks = 0; ks < KSPLIT; ++ks) s += partial[(size_t)ks * OUTTOT + idx];
  int n = idx & 127;
  if (n >= 64) s += LPb[n - 64];
  hcat[idx] = s;
}

// ---- K4: GCN1 edge scatter: gb[c][j] += h1[r][j]*dinv[r]*dinv[c]
__global__ __launch_bounds__(256) void k_sc1(const int* __restrict__ e32, int E,
                                             const int* __restrict__ flag,
                                             const float* __restrict__ dinv,
                                             const float* __restrict__ hcat,
                                             float* __restrict__ gb) {
  int j = threadIdx.x & 63;
  int wv = threadIdx.x >> 6;
  int base = blockIdx.x * 32 + wv * 8;
  bool i64 = (*flag != 0);
  for (int i = 0; i < 8; ++i) {
    int e = base + i;
    if (e >= E) break;
    int r = i64 ? e32[2 * e] : e32[e];
    int c = i64 ? e32[2 * E + 2 * e] : e32[E + e];
    float v = hcat[r * LL + j] * dinv[r] * dinv[c];
    atomicAdd(&gb[c * HH + j], v);
  }
}

// ---- K5: h = res + GCN1 (+self loop), SiLU, global LayerNorm -> hn
__global__ __launch_bounds__(1024) void k_mid(const float* __restrict__ hcat,
                                              const float* __restrict__ gb,
                                              const float* __restrict__ b1,
                                              const float* __restrict__ dinv,
                                              float* __restrict__ hn) {
  int tid = threadIdx.x;
  float sum = 0.f, sq = 0.f;
  for (int idx = tid; idx < TOT; idx += 1024) {
    int m = idx >> 6, j = idx & 63;
    float di = dinv[m];
    float t = hcat[(m << 7) + 64 + j] + b1[j] + gb[idx] + hcat[(m << 7) + j] * di * di;
    float s = t / (1.f + __expf(-t));
    hn[idx] = s;
    sum += s; sq += s * s;
  }
#pragma unroll
  for (int o = 32; o; o >>= 1) { sum += __shfl_down(sum, o); sq += __shfl_down(sq, o); }
  __shared__ float ls[16], lq[16];
  __shared__ float mu_s, rs_s;
  int wv = tid >> 6;
  if ((tid & 63) == 0) { ls[wv] = sum; lq[wv] = sq; }
  __syncthreads();
  if (tid == 0) {
    float S = 0.f, Q = 0.f;
    for (int i = 0; i < 16; ++i) { S += ls[i]; Q += lq[i]; }
    float mu = S / (float)TOT;
    float var = Q / (float)TOT - mu * mu;
    mu_s = mu;
    rs_s = rsqrtf(var + 1e-5f);
  }
  __syncthreads();
  float mu = mu_s, rs = rs_s;
  for (int idx = tid; idx < TOT; idx += 1024) hn[idx] = (hn[idx] - mu) * rs;
}

// ---- K6: hw'[i][j] = (hn[i]@W2)[j]*dinv[i]; out init = b2 + self-loop term
__global__ __launch_bounds__(256) void k_g2(const float* __restrict__ hn,
                                            const float* __restrict__ W2,
                                            const float* __restrict__ b2,
                                            const float* __restrict__ dinv,
                                            float* __restrict__ hw,
                                            float* __restrict__ out) {
  __shared__ float w2s[HH * LL];
  for (int i = threadIdx.x; i < HH * LL; i += 256) w2s[i] = W2[i];
  __syncthreads();
  int idx = blockIdx.x * 256 + threadIdx.x;
  int i = idx >> 7, j = idx & 127;
  float acc = 0.f;
#pragma unroll
  for (int k = 0; k < HH; ++k) acc += hn[i * HH + k] * w2s[k * LL + j];
  float di = dinv[i];
  float hv = acc * di;
  hw[idx] = hv;
  out[idx] = b2[j] + hv * di;
}

// ---- K7: GCN2 edge scatter: out[c][j] += hw'[r][j]*dinv[c]
__global__ __launch_bounds__(256) void k_sc2(const int* __restrict__ e32, int E,
                                             const int* __restrict__ flag,
                                             const float* __restrict__ dinv,
                                             const float* __restrict__ hw,
                                             float* __restrict__ out) {
  int j = threadIdx.x & 127;
  int h = threadIdx.x >> 7;
  int base = blockIdx.x * 16 + h * 8;
  bool i64 = (*flag != 0);
  for (int i = 0; i < 8; ++i) {
    int e = base + i;
    if (e >= E) break;
    int r = i64 ? e32[2 * e] : e32[e];
    int c = i64 ? e32[2 * E + 2 * e] : e32[E + e];
    float v = hw[r * LL + j] * dinv[c];
    atomicAdd(&out[c * LL + j], v);
  }
}

extern "C" void kernel_launch(void* const* d_in, const int* in_sizes, int n_in,
                              void* d_out, int out_size, void* d_ws, size_t ws_size,
                              hipStream_t stream) {
  const float* x   = (const float*)d_in[0];
  const int*   e32 = (const int*)d_in[1];
  const float* W1  = (const float*)d_in[2];
  const float* b1  = (const float*)d_in[3];
  const float* W2  = (const float*)d_in[4];
  const float* b2  = (const float*)d_in[5];
  const float* LPw = (const float*)d_in[6];
  const float* LPb = (const float*)d_in[7];
  int E = in_sizes[1] / 2;
  float* out = (float*)d_out;

  char* ws = (char*)d_ws;
  size_t o_wt      = 0;                                // 8,396,800 B
  size_t o_partial = o_wt + (size_t)128 * WT_STRIDE * 2;     // 10,584,064 B
  size_t o_hcat    = o_partial + (size_t)KSPLIT * OUTTOT * 4;
  size_t o_g       = o_hcat + (size_t)OUTTOT * 4;
  size_t o_hn      = o_g + (size_t)TOT * 4;
  size_t o_hw      = o_hn + (size_t)TOT * 4;
  size_t o_dinv    = o_hw + (size_t)OUTTOT * 4;
  size_t o_flag    = o_dinv + 2816;

  unsigned short* wt = (unsigned short*)(ws + o_wt);
  float* partial = (float*)(ws + o_partial);
  float* hcat    = (float*)(ws + o_hcat);
  float* gb      = (float*)(ws + o_g);
  float* hn      = (float*)(ws + o_hn);
  float* hw      = (float*)(ws + o_hw);
  float* dinv    = (float*)(ws + o_dinv);
  int*   flag    = (int*)(ws + o_flag);

  hipMemsetAsync(gb, 0, (size_t)TOT * 4, stream);

  k_wt<<<FF / 64, 256, 0, stream>>>(W1, LPw, wt);
  k_deg<<<1, 1024, 0, stream>>>(e32, E, dinv, flag);
  k_gemm<<<dim3(21, KSPLIT), 256, 0, stream>>>(x, wt, partial);
  k_red<<<OUTTOT / 256, 256, 0, stream>>>(partial, LPb, hcat);
  k_sc1<<<(E + 31) / 32, 256, 0, stream>>>(e32, E, flag, dinv, hcat, gb);
  k_mid<<<1, 1024, 0, stream>>>(hcat, gb, b1, dinv, hn);
  k_g2<<<OUTTOT / 256, 256, 0, stream>>>(hn, W2, b2, dinv, hw, out);
  k_sc2<<<(E + 15) / 16, 256, 0, stream>>>(e32, E, flag, dinv, hw, out);
}

// Round 2
// 127.839 us; speedup vs baseline: 1.1284x; 1.1284x over previous
//
#include <hip/hip_runtime.h>
#include <hip/hip_bf16.h>

#define NN 646
#define FF 32768
#define HH 64
#define LL 128
#define TOT (NN*HH)          // 41344
#define OUTTOT (NN*LL)       // 82688
#define WT_STRIDE (FF + 32)  // padded bf16 row

typedef float f32x4 __attribute__((ext_vector_type(4)));
typedef short short8 __attribute__((ext_vector_type(8)));

__device__ __forceinline__ unsigned short f2bf(float f) {
  __hip_bfloat16 h = __float2bfloat16(f);
  return __builtin_bit_cast(unsigned short, h);
}
__device__ __forceinline__ short8 pack8(float4 u, float4 v) {
  short8 r;
  r[0] = (short)f2bf(u.x); r[1] = (short)f2bf(u.y);
  r[2] = (short)f2bf(u.z); r[3] = (short)f2bf(u.w);
  r[4] = (short)f2bf(v.x); r[5] = (short)f2bf(v.y);
  r[6] = (short)f2bf(v.z); r[7] = (short)f2bf(v.w);
  return r;
}

// ---- K0: transpose+convert [W1|LPw] -> wt bf16 [128][WT_STRIDE]
__global__ __launch_bounds__(256) void k_wt(const float* __restrict__ W1,
                                            const float* __restrict__ LPw,
                                            unsigned short* __restrict__ wt) {
  __shared__ float t[64][129];
  int k0 = blockIdx.x * 64;
  for (int idx = threadIdx.x; idx < 64 * 128; idx += 256) {
    int kk = idx >> 7, n = idx & 127;
    float v = (n < 64) ? W1[(size_t)(k0 + kk) * 64 + n]
                       : LPw[(size_t)(k0 + kk) * 64 + (n - 64)];
    t[kk][n] = v;
  }
  __syncthreads();
  for (int idx = threadIdx.x; idx < 64 * 128; idx += 256) {
    int kk = idx & 63, n = idx >> 6;
    wt[(size_t)n * WT_STRIDE + k0 + kk] = f2bf(t[kk][n]);
  }
}

// ---- K1: degrees, dinv, CSR offsets (block scan), zero cursors, dtype flag
__global__ __launch_bounds__(1024) void k_deg(const int* __restrict__ e32, int E,
                                              float* __restrict__ dinv,
                                              int* __restrict__ offsets,
                                              int* __restrict__ cursor,
                                              int* __restrict__ flag) {
  __shared__ int cnt[1024];
  __shared__ int scan[1024];
  __shared__ int orred;
  int tid = threadIdx.x;
  if (tid == 0) orred = 0;
  cnt[tid] = 0;
  __syncthreads();
  if (tid < E && e32[2 * tid + 1] != 0) atomicOr(&orred, 1);
  __syncthreads();
  bool i64 = (orred == 0);
  const int* cp = i64 ? (e32 + 2 * (size_t)E) : (e32 + E);
  int cst = i64 ? 2 : 1;
  for (int e = tid; e < E; e += 1024) atomicAdd(&cnt[cp[(size_t)e * cst]], 1);
  __syncthreads();
  int v = cnt[tid];
  scan[tid] = v;
  __syncthreads();
  for (int d = 1; d < 1024; d <<= 1) {
    int t = (tid >= d) ? scan[tid - d] : 0;
    __syncthreads();
    scan[tid] += t;
    __syncthreads();
  }
  if (tid < NN) {
    offsets[tid] = scan[tid] - v;   // exclusive prefix
    dinv[tid] = rsqrtf((float)(v + 1));
    cursor[tid] = 0;
  }
  if (tid == 0) { offsets[NN] = E; *flag = i64 ? 1 : 0; }
}

// ---- K2: CSR placement (sources grouped by target)
__global__ __launch_bounds__(256) void k_place(const int* __restrict__ e32, int E,
                                               const int* __restrict__ flag,
                                               const int* __restrict__ offsets,
                                               int* __restrict__ cursor,
                                               int* __restrict__ srcs) {
  int e = blockIdx.x * 256 + threadIdx.x;
  if (e >= E) return;
  bool i64 = (*flag != 0);
  int r = i64 ? e32[2 * e] : e32[e];
  int c = i64 ? e32[2 * (size_t)E + 2 * e] : e32[E + e];
  int p = atomicAdd(&cursor[c], 1);
  srcs[offsets[c] + p] = r;
}

// ---- K3: split-K GEMM with register ping-pong A prefetch
template <int KSLICE>
__global__ __launch_bounds__(256) void k_gemm(const float* __restrict__ x,
                                              const unsigned short* __restrict__ wt,
                                              float* __restrict__ partial) {
  int mt = blockIdx.x;
  int ks = blockIdx.y;
  int tid = threadIdx.x;
  int w = tid >> 6, l = tid & 63;
  int mh = w & 1, nh = w >> 1;
  int lr = l & 15, g = l >> 4;
  int row = mt * 32 + mh * 16 + lr;
  int rc = row < NN ? row : NN - 1;
  const float* xp = x + (size_t)rc * FF + ks * KSLICE + g * 8;
  const unsigned short* wp = wt + (size_t)(nh * 64 + lr) * WT_STRIDE + ks * KSLICE + g * 8;
  f32x4 ac0 = {0.f, 0.f, 0.f, 0.f}, ac1 = ac0, ac2 = ac0, ac3 = ac0;

  auto LOADA = [&](float4* d, int q) {
#pragma unroll
    for (int s = 0; s < 4; ++s) {
      d[2 * s]     = *reinterpret_cast<const float4*>(xp + q * 128 + s * 32);
      d[2 * s + 1] = *reinterpret_cast<const float4*>(xp + q * 128 + s * 32 + 4);
    }
  };
  auto COMP = [&](const float4* d, int q) {
#pragma unroll
    for (int s = 0; s < 4; ++s) {
      int kk = q * 128 + s * 32;
      short8 av = pack8(d[2 * s], d[2 * s + 1]);
      short8 b0 = *reinterpret_cast<const short8*>(wp + kk);
      short8 b1 = *reinterpret_cast<const short8*>(wp + kk + 16 * WT_STRIDE);
      short8 b2 = *reinterpret_cast<const short8*>(wp + kk + 32 * WT_STRIDE);
      short8 b3 = *reinterpret_cast<const short8*>(wp + kk + 48 * WT_STRIDE);
      ac0 = __builtin_amdgcn_mfma_f32_16x16x32_bf16(av, b0, ac0, 0, 0, 0);
      ac1 = __builtin_amdgcn_mfma_f32_16x16x32_bf16(av, b1, ac1, 0, 0, 0);
      ac2 = __builtin_amdgcn_mfma_f32_16x16x32_bf16(av, b2, ac2, 0, 0, 0);
      ac3 = __builtin_amdgcn_mfma_f32_16x16x32_bf16(av, b3, ac3, 0, 0, 0);
    }
  };

  constexpr int NQ = KSLICE / 128;
  float4 pA[8], pB[8];
  LOADA(pA, 0);
#pragma unroll
  for (int q = 0; q < NQ; ++q) {
    if (q & 1) {
      if (q + 1 < NQ) LOADA(pA, q + 1);
      COMP(pB, q);
    } else {
      if (q + 1 < NQ) LOADA(pB, q + 1);
      COMP(pA, q);
    }
  }

  int mbase = mt * 32 + mh * 16 + g * 4;
  int nb = nh * 64 + lr;
  float* pp = partial + (size_t)ks * OUTTOT;
#pragma unroll
  for (int j = 0; j < 4; ++j) {
    int m = mbase + j;
    if (m < NN) {
      pp[m * LL + nb +  0] = ac0[j];
      pp[m * LL + nb + 16] = ac1[j];
      pp[m * LL + nb + 32] = ac2[j];
      pp[m * LL + nb + 48] = ac3[j];
    }
  }
}

// ---- K4: reduce partials (float4), add LPb to cols 64..127
template <int KSP>
__global__ __launch_bounds__(256) void k_red(const float* __restrict__ partial,
                                             const float* __restrict__ LPb,
                                             float* __restrict__ hcat) {
  int i4 = blockIdx.x * 256 + threadIdx.x;
  if (i4 * 4 >= OUTTOT) return;
  f32x4 s = {0.f, 0.f, 0.f, 0.f};
#pragma unroll 8
  for (int ks = 0; ks < KSP; ++ks)
    s += *reinterpret_cast<const f32x4*>(partial + (size_t)ks * OUTTOT + i4 * 4);
  int n = (i4 * 4) & 127;
  if (n & 64) s += *reinterpret_cast<const f32x4*>(LPb + (n - 64));
  *reinterpret_cast<f32x4*>(hcat + i4 * 4) = s;
}

// ---- K5: GCN1 gather: gb[c][j] = dinv[c] * sum_r h1[r][j]*dinv[r]
__global__ __launch_bounds__(256) void k_agg1(const int* __restrict__ offsets,
                                              const int* __restrict__ srcs,
                                              const float* __restrict__ dinv,
                                              const float* __restrict__ hcat,
                                              float* __restrict__ gb) {
  int c = blockIdx.x;
  int j = threadIdx.x & 63, qt = threadIdx.x >> 6;
  int o0 = offsets[c], o1 = offsets[c + 1];
  float acc = 0.f;
  for (int i = o0 + qt; i < o1; i += 4) {
    int r = srcs[i];
    acc += hcat[r * LL + j] * dinv[r];
  }
  __shared__ float red[4][64];
  red[qt][j] = acc;
  __syncthreads();
  if (qt == 0)
    gb[c * HH + j] = (red[0][j] + red[1][j] + red[2][j] + red[3][j]) * dinv[c];
}

// ---- K6: res + GCN1 + b1 + self-loop, SiLU, partial LN stats
__global__ __launch_bounds__(256) void k_silu(const float* __restrict__ hcat,
                                              const float* __restrict__ gb,
                                              const float* __restrict__ b1,
                                              const float* __restrict__ dinv,
                                              float* __restrict__ hn,
                                              float* __restrict__ stats) {
  int idx = blockIdx.x * 256 + threadIdx.x;
  float sum = 0.f, sq = 0.f;
  if (idx < TOT) {
    int m = idx >> 6, j = idx & 63;
    float di = dinv[m];
    float t = hcat[(m << 7) + 64 + j] + b1[j] + gb[idx] + hcat[(m << 7) + j] * di * di;
    float s = t / (1.f + __expf(-t));
    hn[idx] = s;
    sum = s; sq = s * s;
  }
#pragma unroll
  for (int o = 32; o; o >>= 1) { sum += __shfl_down(sum, o); sq += __shfl_down(sq, o); }
  __shared__ float ls[4], lq[4];
  int wv = threadIdx.x >> 6;
  if ((threadIdx.x & 63) == 0) { ls[wv] = sum; lq[wv] = sq; }
  __syncthreads();
  if (threadIdx.x == 0) {
    atomicAdd(&stats[0], ls[0] + ls[1] + ls[2] + ls[3]);
    atomicAdd(&stats[1], lq[0] + lq[1] + lq[2] + lq[3]);
  }
}

// ---- K7: normalize
__global__ __launch_bounds__(256) void k_norm(float* __restrict__ hn,
                                              const float* __restrict__ stats) {
  int idx = blockIdx.x * 256 + threadIdx.x;
  float mu = stats[0] * (1.f / TOT);
  float var = stats[1] * (1.f / TOT) - mu * mu;
  float rs = rsqrtf(var + 1e-5f);
  if (idx < TOT) hn[idx] = (hn[idx] - mu) * rs;
}

// ---- K8: hw[i][j] = (hn[i]@W2)[j] * dinv[i]
__global__ __launch_bounds__(256) void k_g2(const float* __restrict__ hn,
                                            const float* __restrict__ W2,
                                            const float* __restrict__ dinv,
                                            float* __restrict__ hw) {
  __shared__ float w2s[HH * LL];
  for (int i = threadIdx.x; i < HH * LL; i += 256) w2s[i] = W2[i];
  __syncthreads();
  int idx = blockIdx.x * 256 + threadIdx.x;
  int i = idx >> 7, j = idx & 127;
  float acc = 0.f;
#pragma unroll
  for (int k = 0; k < HH; ++k) acc += hn[i * HH + k] * w2s[k * LL + j];
  hw[idx] = acc * dinv[i];
}

// ---- K9: GCN2 gather + bias + self loop
__global__ __launch_bounds__(256) void k_agg2(const int* __restrict__ offsets,
                                              const int* __restrict__ srcs,
                                              const float* __restrict__ dinv,
                                              const float* __restrict__ hw,
                                              const float* __restrict__ b2,
                                              float* __restrict__ out) {
  int c = blockIdx.x;
  int j = threadIdx.x & 127, hf = threadIdx.x >> 7;
  int o0 = offsets[c], o1 = offsets[c + 1];
  float acc = 0.f;
  for (int i = o0 + hf; i < o1; i += 2) acc += hw[srcs[i] * LL + j];
  __shared__ float red[2][128];
  red[hf][j] = acc;
  __syncthreads();
  if (hf == 0)
    out[c * LL + j] = b2[j] + dinv[c] * (red[0][j] + red[1][j] + hw[c * LL + j]);
}

extern "C" void kernel_launch(void* const* d_in, const int* in_sizes, int n_in,
                              void* d_out, int out_size, void* d_ws, size_t ws_size,
                              hipStream_t stream) {
  const float* x   = (const float*)d_in[0];
  const int*   e32 = (const int*)d_in[1];
  const float* W1  = (const float*)d_in[2];
  const float* b1  = (const float*)d_in[3];
  const float* W2  = (const float*)d_in[4];
  const float* b2  = (const float*)d_in[5];
  const float* LPw = (const float*)d_in[6];
  const float* LPb = (const float*)d_in[7];
  int E = in_sizes[1] / 2;
  float* out = (float*)d_out;

  char* ws = (char*)d_ws;
  size_t wt_b = (size_t)128 * WT_STRIDE * 2;               // 8,396,800
  size_t tail = 330752 + 3 * 2816 + 165376 + 512;          // hcat + dinv/offs/cur + srcs + stats/flag
  size_t need64 = wt_b + (size_t)64 * OUTTOT * 4 + tail;
  int ksplit = (ws_size >= need64) ? 64 : 32;
  size_t part_b = (size_t)ksplit * OUTTOT * 4;

  size_t o_partial = wt_b;
  size_t o_gb   = o_partial;                 // aliases partial (dead after k_red)
  size_t o_hn   = o_partial + 165376;
  size_t o_hw   = o_hn + 165376;
  size_t o_hcat = o_partial + part_b;
  size_t o_dinv = o_hcat + 330752;
  size_t o_offs = o_dinv + 2816;
  size_t o_cur  = o_offs + 2816;
  size_t o_srcs = o_cur + 2816;
  size_t o_stat = o_srcs + 165376;
  size_t o_flag = o_stat + 256;

  unsigned short* wt = (unsigned short*)ws;
  float* partial = (float*)(ws + o_partial);
  float* gb      = (float*)(ws + o_gb);
  float* hn      = (float*)(ws + o_hn);
  float* hw      = (float*)(ws + o_hw);
  float* hcat    = (float*)(ws + o_hcat);
  float* dinv    = (float*)(ws + o_dinv);
  int*   offs    = (int*)(ws + o_offs);
  int*   cursor  = (int*)(ws + o_cur);
  int*   srcs    = (int*)(ws + o_srcs);
  float* stats   = (float*)(ws + o_stat);
  int*   flag    = (int*)(ws + o_flag);

  hipMemsetAsync(stats, 0, 8, stream);
  k_wt<<<FF / 64, 256, 0, stream>>>(W1, LPw, wt);
  k_deg<<<1, 1024, 0, stream>>>(e32, E, dinv, offs, cursor, flag);
  k_place<<<(E + 255) / 256, 256, 0, stream>>>(e32, E, flag, offs, cursor, srcs);
  if (ksplit == 64) {
    k_gemm<512><<<dim3(21, 64), 256, 0, stream>>>(x, wt, partial);
    k_red<64><<<(OUTTOT / 4 + 255) / 256, 256, 0, stream>>>(partial, LPb, hcat);
  } else {
    k_gemm<1024><<<dim3(21, 32), 256, 0, stream>>>(x, wt, partial);
    k_red<32><<<(OUTTOT / 4 + 255) / 256, 256, 0, stream>>>(partial, LPb, hcat);
  }
  k_agg1<<<NN, 256, 0, stream>>>(offs, srcs, dinv, hcat, gb);
  k_silu<<<(TOT + 255) / 256, 256, 0, stream>>>(hcat, gb, b1, dinv, hn, stats);
  k_norm<<<(TOT + 255) / 256, 256, 0, stream>>>(hn, stats);
  k_g2<<<OUTTOT / 256, 256, 0, stream>>>(hn, W2, dinv, hw);
  k_agg2<<<NN, 256, 0, stream>>>(offs, srcs, dinv, hw, b2, out);
}